// Round 27
// baseline (144.246 us; speedup 1.0000x reference)
//
#include <hip/hip_runtime.h>
#include <hip/hip_bf16.h>
#include <math.h>
#include <stdint.h>

typedef __attribute__((ext_vector_type(8))) short short8;
typedef __attribute__((ext_vector_type(4))) float f32x4;
typedef __attribute__((ext_vector_type(16))) float f32x16;

#define BM 256
#define NKT 36
#define A_BYTES (BM * 128)          // 32 KiB per A buffer (8 units x 256 rows x 16B)
#define LDS_TOTAL (4 * A_BYTES)     // 128 KiB: 1 block/CU (REQUIRED: 2-block
                                    // co-residency corrupts; R8/R9/R10/R23)

__device__ __forceinline__ unsigned short f2bf(float f) {
    __bf16 h = (__bf16)f;
    return __builtin_bit_cast(unsigned short, h);
}

__device__ __forceinline__ float gelu_exact(float x) {
    return 0.5f * x * (1.0f + erff(x * 0.7071067811865475f));
}

// UNIT-MAJOR A-tile layout (verified R26, zero bank conflicts):
// byte addr of (row, unit) = unit*4096 + row*16.

// Frag-major weight image for 32x32x16 MFMA (verified R25/R26): 16B unit
// U = kt*2048 + wc*512 + i*64 + lane, i = ks*2 + nt.
// Unit holds W[o][k0..k0+8) with o = wc*64 + (i&1)*32 + (lane&31),
// k0 = kt*64 + (i>>1)*16 + (lane>>5)*8.
__global__ void kan_prep_w(const float* __restrict__ bw, const float* __restrict__ sw,
                           unsigned short* __restrict__ Wf) {
    int U = blockIdx.x * 256 + threadIdx.x;   // 36*2048 units
    if (U >= NKT * 2048) return;
    int kt = U >> 11, rem = U & 2047;
    int wcq = rem >> 9, rem2 = rem & 511;
    int i = rem2 >> 6;                 // ks*2 + nt
    int lane = rem2 & 63;
    int o = wcq * 64 + (i & 1) * 32 + (lane & 31);
    int k0 = kt * 64 + (i >> 1) * 16 + (lane >> 5) * 8;
    unsigned short pk[8];
#pragma unroll
    for (int e = 0; e < 8; ++e) {
        int kk = k0 + e;
        float v = (kk < 256) ? bw[o * 256 + kk] : sw[o * 2048 + (kk - 256)];
        pk[e] = f2bf(v);
    }
    *(short8*)(Wf + (size_t)U * 8) = *(short8*)pk;
}

// spline: 16B unit (8 basis slots, 4 nonzero) via funnel shift (verified R2)
__device__ __forceinline__ short8 spline_row(float xv) {
    float xi = (xv + 2.2f) * 2.5f;
    float fi = floorf(xi);
    float tt = xi - fi;
    float s1 = 1.0f - tt;
    float t2 = tt * tt, t3 = t2 * tt;
    float w0 = s1 * s1 * s1 * (1.0f / 6.0f);
    float w1 = 0.5f * t3 - t2 + (2.0f / 3.0f);
    float w2 = -0.5f * t3 + 0.5f * t2 + 0.5f * tt + (1.0f / 6.0f);
    float w3 = t3 * (1.0f / 6.0f);
    uint64_t Wp = (uint64_t)f2bf(w0) | ((uint64_t)f2bf(w1) << 16)
                | ((uint64_t)f2bf(w2) << 32) | ((uint64_t)f2bf(w3) << 48);
    int b = 16 * ((int)fi - 3);
    uint64_t L = (b >= 0 && b < 64) ? (Wp << b)
               : ((b < 0 && b > -64) ? (Wp >> (-b)) : 0ull);
    uint64_t H = (b >= 64 && b < 128) ? (Wp << (b - 64))
               : ((b > 0 && b < 64) ? (Wp >> (64 - b)) : 0ull);
    union { uint64_t q[2]; short8 v; } rr;
    rr.q[0] = L; rr.q[1] = H;
    return rr.v;
}

__global__ __launch_bounds__(512)   // 8 waves = 2/SIMD; no occupancy pin (R8-R10 rule)
void kan_fused(
    const float* __restrict__ X, const unsigned short* __restrict__ Wf,
    const float* __restrict__ gamma, const float* __restrict__ beta,
    const float* __restrict__ prelu_a, float* __restrict__ OUT)
{
    extern __shared__ __align__(16) unsigned char lds[];   // 4 x 32K A ring

    const int t = threadIdx.x;
    const int row0 = blockIdx.x * BM;
    const int wid = t >> 6, lane = t & 63;
    const int wr = wid >> 2, wc = wid & 3;      // 2 x 4 waves; wave tile 128x64
    const int l31 = lane & 31, l5 = lane >> 5;
    const int sr = t & 255, su = (t >> 8) * 4;  // staging: row sr, units su..su+3

    f32x16 acc[4][2];
#pragma unroll
    for (int mt = 0; mt < 4; ++mt)
#pragma unroll
        for (int nt = 0; nt < 2; ++nt)
#pragma unroll
            for (int e = 0; e < 16; ++e) acc[mt][nt][e] = 0.f;

    const unsigned short* wlane = Wf + ((size_t)wc * 512 + lane) * 8;
    short8 wv[8];

    auto w_load = [&](int kt) {
        const unsigned short* wsrc = wlane + (size_t)kt * 2048 * 8;
#pragma unroll
        for (int i = 0; i < 8; ++i)
            wv[i] = *(const short8*)(wsrc + i * 512);
    };
    auto gelu_stage = [&](int kt, unsigned char* D) {
        const float* xp = X + (size_t)(row0 + sr) * 256 + kt * 64 + su * 8;
        float v[32];
#pragma unroll
        for (int j = 0; j < 8; ++j) {
            float4 t4 = *(const float4*)(xp + j * 4);
            v[j * 4 + 0] = t4.x; v[j * 4 + 1] = t4.y;
            v[j * 4 + 2] = t4.z; v[j * 4 + 3] = t4.w;
        }
#pragma unroll
        for (int j = 0; j < 4; ++j) {
            unsigned short pk[8];
#pragma unroll
            for (int e = 0; e < 8; ++e) pk[e] = f2bf(gelu_exact(v[j * 8 + e]));
            *(short8*)(D + (su + j) * 4096 + sr * 16) = *(short8*)pk;
        }
    };
    auto spline_stage = [&](float4 xs, unsigned char* D) {
        *(short8*)(D + (su + 0) * 4096 + sr * 16) = spline_row(xs.x);
        *(short8*)(D + (su + 1) * 4096 + sr * 16) = spline_row(xs.y);
        *(short8*)(D + (su + 2) * 4096 + sr * 16) = spline_row(xs.z);
        *(short8*)(D + (su + 3) * 4096 + sr * 16) = spline_row(xs.w);
    };
    auto mfma_tile = [&](unsigned char* B) {
        __builtin_amdgcn_s_setprio(1);
#pragma unroll
        for (int ks = 0; ks < 4; ++ks) {
            short8 af[4];
#pragma unroll
            for (int mt = 0; mt < 4; ++mt)
                af[mt] = *(const short8*)(B + (ks * 2 + l5) * 4096
                                          + (wr * 128 + mt * 32 + l31) * 16);
#pragma unroll
            for (int mt = 0; mt < 4; ++mt)
#pragma unroll
                for (int nt = 0; nt < 2; ++nt)
                    acc[mt][nt] = __builtin_amdgcn_mfma_f32_32x32x16_bf16(
                        af[mt], wv[ks * 2 + nt], acc[mt][nt], 0, 0, 0);
        }
        __builtin_amdgcn_s_setprio(0);
    };

    // period body: consumes (curA,curB) = spline x for THIS period's staged
    // tiles (loaded one full period ago); prefetches (nxtA,nxtB) for NEXT
    // period (~17K-cycle load-to-use distance -> HBM latency fully covered)
    auto body = [&](int j, float4& curA, float4& curB, float4& nxtA, float4& nxtB) {
        const int ka = 2 * j, kb = ka + 1;
        unsigned char* Ba = lds + (ka & 3) * A_BYTES;
        unsigned char* Bb = lds + (kb & 3) * A_BYTES;
        unsigned char* Sa = lds + ((ka + 2) & 3) * A_BYTES;
        unsigned char* Sb = lds + ((ka + 3) & 3) * A_BYTES;
        const bool stg = (ka + 2 < NKT);
        const bool gA = (ka + 2 < 4), gB = (ka + 3 < 4);

        // distance-1-period prefetch (tiles ka+4, ka+5 are always spline)
        if (ka + 4 < NKT) {
            nxtA = *(const float4*)(X + (size_t)(row0 + sr) * 256 + (ka + 4 - 4) * 8 + su);
            nxtB = *(const float4*)(X + (size_t)(row0 + sr) * 256 + (ka + 5 - 4) * 8 + su);
        }

        if ((wid & 1) == 0) {
            mfma_tile(Ba);                 // wv(ka)
            w_load(kb);
            if (stg) { if (gA) gelu_stage(ka + 2, Sa); else spline_stage(curA, Sa); }
            mfma_tile(Bb);                 // wv(kb)
            if (stg) w_load(ka + 2);
            if (stg) { if (gB) gelu_stage(ka + 3, Sb); else spline_stage(curB, Sb); }
        } else {
            if (stg) { if (gA) gelu_stage(ka + 2, Sa); else spline_stage(curA, Sa); }
            mfma_tile(Ba);                 // wv(ka)
            w_load(kb);
            if (stg) { if (gB) gelu_stage(ka + 3, Sb); else spline_stage(curB, Sb); }
            mfma_tile(Bb);                 // wv(kb)
            if (stg) w_load(ka + 2);
        }

        asm volatile("s_waitcnt lgkmcnt(0)\n\ts_barrier" ::: "memory");
    };

    // ---- prologue: W(0) -> wv; gelu tiles 0,1 -> buf0,buf1 ----
    w_load(0);
    gelu_stage(0, lds);
    gelu_stage(1, lds + A_BYTES);
    asm volatile("s_waitcnt lgkmcnt(0)\n\ts_barrier" ::: "memory");

    // ---- main loop: 18 periods, 2x unrolled (named cur/nxt pairs, rule #20).
    // Period 0 stages gelu tiles (cur unused); its prefetch seeds period 1.
    float4 xA0 = {0, 0, 0, 0}, xB0 = {0, 0, 0, 0};
    float4 xA1 = {0, 0, 0, 0}, xB1 = {0, 0, 0, 0};
    for (int jj = 0; jj < NKT / 4; ++jj) {      // 9 double-periods
        body(2 * jj,     xA0, xB0, xA1, xB1);
        body(2 * jj + 1, xA1, xB1, xA0, xB0);
    }

    // ---- fused LayerNorm + PReLU epilogue (32x32 C/D, verified R25/R26) ----
    float* stats = (float*)lds;   // [256][8]: 4 col-partial sums, 4 col-partial sumsq
#pragma unroll
    for (int mt = 0; mt < 4; ++mt) {
#pragma unroll
        for (int r = 0; r < 16; ++r) {
            float v0 = acc[mt][0][r], v1 = acc[mt][1][r];
            float s = v0 + v1, s2 = v0 * v0 + v1 * v1;
#pragma unroll
            for (int msk = 1; msk < 32; msk <<= 1) {
                s  += __shfl_xor(s,  msk, 64);
                s2 += __shfl_xor(s2, msk, 64);
            }
            int row_local = (r & 3) + 8 * (r >> 2) + 4 * l5;
            if (l31 == row_local) {
                int row = wr * 128 + mt * 32 + row_local;
                stats[row * 8 + wc]     = s;
                stats[row * 8 + 4 + wc] = s2;
            }
        }
    }
    __syncthreads();

    const float apr = prelu_a[0];
    float gv[2], bv[2];
#pragma unroll
    for (int nt = 0; nt < 2; ++nt) {
        int col = wc * 64 + nt * 32 + l31;
        gv[nt] = gamma[col]; bv[nt] = beta[col];
    }
#pragma unroll
    for (int mt = 0; mt < 4; ++mt) {
#pragma unroll
        for (int r = 0; r < 16; ++r) {
            int row = wr * 128 + mt * 32 + (r & 3) + 8 * (r >> 2) + 4 * l5;
            f32x4 sv = *(const f32x4*)(stats + row * 8);
            f32x4 qv = *(const f32x4*)(stats + row * 8 + 4);
            float mu  = (sv[0] + sv[1] + sv[2] + sv[3]) * (1.0f / 256.0f);
            float ex2 = (qv[0] + qv[1] + qv[2] + qv[3]) * (1.0f / 256.0f);
            float rs = rsqrtf(ex2 - mu * mu + 1e-5f);
            float* op = OUT + (size_t)(row0 + row) * 256;
#pragma unroll
            for (int nt = 0; nt < 2; ++nt) {
                int col = wc * 64 + nt * 32 + l31;
                float y = (acc[mt][nt][r] - mu) * rs * gv[nt] + bv[nt];
                op[col] = (y >= 0.f) ? y : apr * y;
            }
        }
    }
}

extern "C" void kernel_launch(void* const* d_in, const int* in_sizes, int n_in,
                              void* d_out, int out_size, void* d_ws, size_t ws_size,
                              hipStream_t stream) {
    const float* x  = (const float*)d_in[0];
    // d_in[1] = grid knots (uniform linspace; constants folded into closed form)
    const float* bw = (const float*)d_in[2];
    const float* sw = (const float*)d_in[3];
    const float* g  = (const float*)d_in[4];
    const float* be = (const float*)d_in[5];
    const float* pa = (const float*)d_in[6];
    float* out = (float*)d_out;
    unsigned short* Wf = (unsigned short*)d_ws;   // 36*2048*16B frag-major (32x32)

    hipFuncSetAttribute((const void*)kan_fused,
                        hipFuncAttributeMaxDynamicSharedMemorySize, LDS_TOTAL);

    const int Nrows = in_sizes[0] / 256;
    kan_prep_w<<<(NKT * 2048 + 255) / 256, 256, 0, stream>>>(bw, sw, Wf);
    kan_fused<<<Nrows / BM, 512, LDS_TOTAL, stream>>>(x, Wf, g, be, pa, out);
}

// Round 28
// 125.013 us; speedup vs baseline: 1.1538x; 1.1538x over previous
//
#include <hip/hip_runtime.h>
#include <hip/hip_bf16.h>
#include <math.h>
#include <stdint.h>

typedef __attribute__((ext_vector_type(8))) short short8;
typedef __attribute__((ext_vector_type(4))) float f32x4;

#define BM 256
#define NKT 36
#define A_BYTES (BM * 128)          // 32 KiB per A buffer
#define LDS_TOTAL (4 * A_BYTES)     // 128 KiB: 4-buffer A ring -> 1 block/CU (REQUIRED:
                                    // 2-block co-residency corrupts; R8/R9/R10/R23)

__device__ __forceinline__ unsigned short f2bf(float f) {
    __bf16 h = (__bf16)f;
    return __builtin_bit_cast(unsigned short, h);
}

__device__ __forceinline__ float gelu_exact(float x) {
    return 0.5f * x * (1.0f + erff(x * 0.7071067811865475f));
}

// swizzled byte offset for 16B unit u of a 64-bf16 (128B) LDS row
__device__ __forceinline__ int swz(int row, int u) {
    return row * 128 + ((u ^ (row & 7)) << 4);
}

// Frag-major weight image (verified R7/R14): 16B unit
// U = kt*2048 + wc*512 + i*64 + lane, i = kh*4 + n.
// Unit holds W[o][k0..k0+8) with o = wc*64 + n*16 + (lane&15),
// k0 = kt*64 + (kh*4 + (lane>>4))*8.
__global__ void kan_prep_w(const float* __restrict__ bw, const float* __restrict__ sw,
                           unsigned short* __restrict__ Wf) {
    int U = blockIdx.x * 256 + threadIdx.x;   // 36*2048 units
    if (U >= NKT * 2048) return;
    int kt = U >> 11, rem = U & 2047;
    int wcq = rem >> 9, rem2 = rem & 511;
    int i = rem2 >> 6;                 // kh*4 + n
    int lane = rem2 & 63;
    int o = wcq * 64 + (i & 3) * 16 + (lane & 15);
    int k0 = kt * 64 + ((i >> 2) * 4 + (lane >> 4)) * 8;
    unsigned short pk[8];
#pragma unroll
    for (int e = 0; e < 8; ++e) {
        int kk = k0 + e;
        float v = (kk < 256) ? bw[o * 256 + kk] : sw[o * 2048 + (kk - 256)];
        pk[e] = f2bf(v);
    }
    *(short8*)(Wf + (size_t)U * 8) = *(short8*)pk;
}

// spline: 16B row image (8 bf16 slots, 4 nonzero) via funnel shift (verified R2)
__device__ __forceinline__ short8 spline_row(float xv) {
    float xi = (xv + 2.2f) * 2.5f;
    float fi = floorf(xi);
    float tt = xi - fi;
    float s1 = 1.0f - tt;
    float t2 = tt * tt, t3 = t2 * tt;
    float w0 = s1 * s1 * s1 * (1.0f / 6.0f);
    float w1 = 0.5f * t3 - t2 + (2.0f / 3.0f);
    float w2 = -0.5f * t3 + 0.5f * t2 + 0.5f * tt + (1.0f / 6.0f);
    float w3 = t3 * (1.0f / 6.0f);
    uint64_t Wp = (uint64_t)f2bf(w0) | ((uint64_t)f2bf(w1) << 16)
                | ((uint64_t)f2bf(w2) << 32) | ((uint64_t)f2bf(w3) << 48);
    int b = 16 * ((int)fi - 3);
    uint64_t L = (b >= 0 && b < 64) ? (Wp << b)
               : ((b < 0 && b > -64) ? (Wp >> (-b)) : 0ull);
    uint64_t H = (b >= 64 && b < 128) ? (Wp << (b - 64))
               : ((b > 0 && b < 64) ? (Wp >> (64 - b)) : 0ull);
    union { uint64_t q[2]; short8 v; } rr;
    rr.q[0] = L; rr.q[1] = H;
    return rr.v;
}

__global__ __launch_bounds__(512)   // 8 waves = 2/SIMD; no occupancy pin (R8-R10 rule)
void kan_fused(
    const float* __restrict__ X, const unsigned short* __restrict__ Wf,
    const float* __restrict__ gamma, const float* __restrict__ beta,
    const float* __restrict__ prelu_a, float* __restrict__ OUT)
{
    extern __shared__ __align__(16) unsigned char lds[];   // 4 x 32K A ring

    const int t = threadIdx.x;
    const int row0 = blockIdx.x * BM;
    const int wid = t >> 6, lane = t & 63;
    const int wr = wid >> 2, wc = wid & 3;      // 2 x 4 waves; wave tile 128x64
    const int lcol = lane & 15, q = lane >> 4;
    const int srow = t >> 3, scol = t & 7;      // staging: 4 reps x 64 rows

    f32x4 acc[8][4];
#pragma unroll
    for (int m = 0; m < 8; ++m)
#pragma unroll
        for (int n = 0; n < 4; ++n) acc[m][n] = (f32x4){0.f, 0.f, 0.f, 0.f};

    const unsigned short* wlane = Wf + ((size_t)wc * 512 + lane) * 8;
    short8 wv[8];

    auto w_load = [&](int kt) {
        const unsigned short* wsrc = wlane + (size_t)kt * 2048 * 8;
#pragma unroll
        for (int i = 0; i < 8; ++i)
            wv[i] = *(const short8*)(wsrc + i * 512);
    };
    auto gelu_stage = [&](int kt, unsigned char* D) {
#pragma unroll
        for (int rep = 0; rep < 4; ++rep) {
            const float* xp = X + (size_t)(row0 + srow + rep * 64) * 256 + kt * 64 + scol * 8;
            float4 v0 = *(const float4*)xp;
            float4 v1 = *(const float4*)(xp + 4);
            float vv[8] = {v0.x, v0.y, v0.z, v0.w, v1.x, v1.y, v1.z, v1.w};
            unsigned short pk[8];
#pragma unroll
            for (int jj = 0; jj < 8; ++jj) pk[jj] = f2bf(gelu_exact(vv[jj]));
            *(short8*)(D + swz(srow + rep * 64, scol)) = *(short8*)pk;
        }
    };
    auto spline_stage = [&](float (&xs)[4], unsigned char* D) {
#pragma unroll
        for (int rep = 0; rep < 4; ++rep)
            *(short8*)(D + swz(srow + rep * 64, scol)) = spline_row(xs[rep]);
    };
    auto mfma_tile = [&](unsigned char* B) {
        __builtin_amdgcn_s_setprio(1);
#pragma unroll
        for (int kh = 0; kh < 2; ++kh) {
            short8 af[8];
#pragma unroll
            for (int m = 0; m < 8; ++m)
                af[m] = *(const short8*)(B + swz(wr * 128 + m * 16 + lcol, kh * 4 + q));
#pragma unroll
            for (int m = 0; m < 8; ++m)
#pragma unroll
                for (int n = 0; n < 4; ++n)
                    acc[m][n] = __builtin_amdgcn_mfma_f32_16x16x32_bf16(
                        af[m], wv[kh * 4 + n], acc[m][n], 0, 0, 0);
        }
        __builtin_amdgcn_s_setprio(0);
    };

    // ---- prologue: W(0) -> wv; gelu tiles 0,1 -> buf0,buf1 ----
    w_load(0);
    gelu_stage(0, lds);
    gelu_stage(1, lds + A_BYTES);
    asm volatile("s_waitcnt lgkmcnt(0)\n\ts_barrier" ::: "memory");

    // ---- main loop: 2 K-tiles/barrier, 4-ring; anti-phase by wid&1 (R22) ----
    for (int j = 0; j < NKT / 2; ++j) {
        const int ka = 2 * j, kb = ka + 1;
        unsigned char* Ba = lds + (ka & 3) * A_BYTES;
        unsigned char* Bb = lds + (kb & 3) * A_BYTES;
        unsigned char* Sa = lds + ((ka + 2) & 3) * A_BYTES;
        unsigned char* Sb = lds + ((ka + 3) & 3) * A_BYTES;
        const bool stg = (ka + 2 < NKT);
        const bool gA = (ka + 2 < 4), gB = (ka + 3 < 4);

        float xsA[4], xsB[4];
        if (stg && !gA) {
            const int ibA = (ka + 2 - 4) * 8;
#pragma unroll
            for (int rep = 0; rep < 4; ++rep)
                xsA[rep] = X[(size_t)(row0 + srow + rep * 64) * 256 + ibA + scol];
        }
        if (stg && !gB) {
            const int ibB = (ka + 3 - 4) * 8;
#pragma unroll
            for (int rep = 0; rep < 4; ++rep)
                xsB[rep] = X[(size_t)(row0 + srow + rep * 64) * 256 + ibB + scol];
        }

        if ((wid & 1) == 0) {
            mfma_tile(Ba);                 // wv(ka)
            w_load(kb);
            if (stg) { if (gA) gelu_stage(ka + 2, Sa); else spline_stage(xsA, Sa); }
            mfma_tile(Bb);                 // wv(kb)
            if (stg) w_load(ka + 2);
            if (stg) { if (gB) gelu_stage(ka + 3, Sb); else spline_stage(xsB, Sb); }
        } else {
            if (stg) { if (gA) gelu_stage(ka + 2, Sa); else spline_stage(xsA, Sa); }
            mfma_tile(Ba);                 // wv(ka)
            w_load(kb);
            if (stg) { if (gB) gelu_stage(ka + 3, Sb); else spline_stage(xsB, Sb); }
            mfma_tile(Bb);                 // wv(kb)
            if (stg) w_load(ka + 2);
        }

        asm volatile("s_waitcnt lgkmcnt(0)\n\ts_barrier" ::: "memory");
    }

    // ---- fused LayerNorm + PReLU epilogue (verified R7/R14) ----
    float* stats = (float*)lds;   // [256][8]: 4 col-partial sums, 4 col-partial sumsq
#pragma unroll
    for (int m = 0; m < 8; ++m) {
#pragma unroll
        for (int r = 0; r < 4; ++r) {
            float s = 0.f, s2 = 0.f;
#pragma unroll
            for (int n = 0; n < 4; ++n) { float v = acc[m][n][r]; s += v; s2 += v * v; }
#pragma unroll
            for (int msk = 1; msk < 16; msk <<= 1) {
                s  += __shfl_xor(s,  msk, 64);
                s2 += __shfl_xor(s2, msk, 64);
            }
            if ((lane & 15) == ((m * 4 + r) & 15)) {
                int row = wr * 128 + m * 16 + q * 4 + r;
                stats[row * 8 + wc]     = s;
                stats[row * 8 + 4 + wc] = s2;
            }
        }
    }
    __syncthreads();

    const float apr = prelu_a[0];
    float gv[4], bv[4];
#pragma unroll
    for (int n = 0; n < 4; ++n) {
        int col = wc * 64 + n * 16 + lcol;
        gv[n] = gamma[col]; bv[n] = beta[col];
    }
#pragma unroll
    for (int m = 0; m < 8; ++m) {
#pragma unroll
        for (int r = 0; r < 4; ++r) {
            int row = wr * 128 + m * 16 + q * 4 + r;
            f32x4 sv = *(const f32x4*)(stats + row * 8);
            f32x4 qv = *(const f32x4*)(stats + row * 8 + 4);
            float mu  = (sv[0] + sv[1] + sv[2] + sv[3]) * (1.0f / 256.0f);
            float ex2 = (qv[0] + qv[1] + qv[2] + qv[3]) * (1.0f / 256.0f);
            float rs = rsqrtf(ex2 - mu * mu + 1e-5f);
            float* op = OUT + (size_t)(row0 + row) * 256;
#pragma unroll
            for (int n = 0; n < 4; ++n) {
                int col = wc * 64 + n * 16 + lcol;
                float y = (acc[m][n][r] - mu) * rs * gv[n] + bv[n];
                op[col] = (y >= 0.f) ? y : apr * y;
            }
        }
    }
}

extern "C" void kernel_launch(void* const* d_in, const int* in_sizes, int n_in,
                              void* d_out, int out_size, void* d_ws, size_t ws_size,
                              hipStream_t stream) {
    const float* x  = (const float*)d_in[0];
    // d_in[1] = grid knots (uniform linspace; constants folded into closed form)
    const float* bw = (const float*)d_in[2];
    const float* sw = (const float*)d_in[3];
    const float* g  = (const float*)d_in[4];
    const float* be = (const float*)d_in[5];
    const float* pa = (const float*)d_in[6];
    float* out = (float*)d_out;
    unsigned short* Wf = (unsigned short*)d_ws;   // 36*2048*16B frag-major

    hipFuncSetAttribute((const void*)kan_fused,
                        hipFuncAttributeMaxDynamicSharedMemorySize, LDS_TOTAL);

    const int Nrows = in_sizes[0] / 256;
    kan_prep_w<<<(NKT * 2048 + 255) / 256, 256, 0, stream>>>(bw, sw, Wf);
    kan_fused<<<Nrows / BM, 512, LDS_TOTAL, stream>>>(x, Wf, g, be, pa, out);
}